// Round 7
// baseline (515.012 us; speedup 1.0000x reference)
//
#include <hip/hip_runtime.h>

// ---------------------------------------------------------------------------
// SharedFusedMoE on MI355X (gfx950). fp32 inputs, FP32 outputs.
// T=4096, D=1024, I=512 (routed), E=16, top-2, SI=2048 (shared).
// Round 13: (a) conv_plus = conversion (512 blocks) + router (1 block) in ONE
// launch; per-block cheap dtype/xsel probes remove the setup->conv dependency,
// hiding the single-block router under the conversion. (b) g2 scatters via
// atomicAdd into memset-zeroed d_out (both ranks -> outF, both shared K-halves
// -> outS): removes add2 kernel, outT/outP buffers. (c) T1 XCD-aware bijective
// block swizzle on g1/g2; g2 shared split-K repacked into z==4 (no idle
// blocks). GEMM inner loop unchanged (T2 swizzle, conflicts measured 0).
// FULL2 sequence: memset(d_out) -> conv_plus -> g1_fused -> g2_fused. 4 nodes.
// Output slot 0 = shared_out, slot 1 = fused_out (reference return order).
// ---------------------------------------------------------------------------

#define T_TOK 4096
#define NEXP  16

typedef __attribute__((ext_vector_type(8))) short   short8;   // 8 x bf16
typedef __attribute__((ext_vector_type(4))) float   floatx4;  // MFMA acc

typedef __attribute__((address_space(1))) void as1_void;
typedef __attribute__((address_space(3))) void as3_void;

__device__ __forceinline__ float bf2f(ushort u) {
    union { unsigned int i; float f; } v; v.i = ((unsigned int)u) << 16; return v.f;
}
__device__ __forceinline__ ushort f2bf(float f) {   // RNE, finite inputs
    unsigned int u = __builtin_bit_cast(unsigned int, f);
    unsigned int r = 0x7FFFu + ((u >> 16) & 1u);
    return (ushort)((u + r) >> 16);
}

__device__ __forceinline__ float load_elem(const void* p, long i, int bf) {
    return bf ? bf2f(((const ushort*)p)[i]) : ((const float*)p)[i];
}

// Router helper: softmax -> top-2 -> renormalize (denominators cancel).
__device__ __forceinline__ void top2(const void* logits, int t, int bf,
                                     int& b0, int& b1, float& w0, float& w1) {
    float l[16];
#pragma unroll
    for (int j = 0; j < 16; ++j) l[j] = load_elem(logits, t * 16 + j, bf);
    b0 = 0; float v0 = l[0];
#pragma unroll
    for (int j = 1; j < 16; ++j) { if (l[j] > v0) { v0 = l[j]; b0 = j; } }
    b1 = -1; float v1 = -3.4e38f;
#pragma unroll
    for (int j = 0; j < 16; ++j) {
        if (j == b0) continue;
        if (l[j] > v1) { v1 = l[j]; b1 = j; }
    }
    float d = __expf(v1 - v0);
    w0 = 1.0f / (1.0f + d);
    w1 = d / (1.0f + d);
}

// ---------------------------------------------------------------------------
// conv_plus: blocks 0..511 convert all five tensors into the contiguous bf16
// region (hidb | w13sb | w13b | w2b | w2sb); block 512 runs the full router
// (counts + scan + pairs, single block, hidden under the conversion). Every
// block self-determines dtype/xsel from small probes (256 + 2x64 samples).
// ---------------------------------------------------------------------------
__global__ __launch_bounds__(1024)
void conv_plus(const void* __restrict__ in0, const void* __restrict__ in4,
               const void* __restrict__ w13, const void* __restrict__ w2,
               const void* __restrict__ w2s, ushort* __restrict__ dst,
               const void* __restrict__ logits,
               int* __restrict__ dflag, int* __restrict__ xsel,
               int* __restrict__ counts, int* __restrict__ offsets,
               int* __restrict__ pairinfo, float* __restrict__ pairw)
{
    const int tid = threadIdx.x;

    // --- cheap per-block probes ---
    __shared__ int   s_ok;
    __shared__ float s0s, s4s;
    if (tid == 0) { s_ok = 0; s0s = 0.f; s4s = 0.f; }
    __syncthreads();
    if (tid < 256) {
        int e = (((const ushort*)in0)[2 * tid] >> 7) & 0xFF;
        if (e >= 90 && e <= 140) atomicAdd(&s_ok, 1);
    }
    __syncthreads();
    const int bf = (s_ok >= 192) ? 1 : 0;
    if (tid < 64) {
        atomicAdd(&s0s, fabsf(load_elem(in0, (long)tid * 997 + 13, bf)));
        atomicAdd(&s4s, fabsf(load_elem(in4, (long)tid * 997 + 13, bf)));
    }
    __syncthreads();
    const int xs = (s0s >= s4s) ? 0 : 1;

    if (blockIdx.x == 512) {
        // ---------------- router block ----------------
        __shared__ int s_cnt[16], s_off[16], s_cur[16];
        if (tid < 16) { s_cnt[tid] = 0; s_cur[tid] = 0; }
        if (tid == 0) { *dflag = bf; *xsel = xs; }
        __syncthreads();
        int   b0[4], b1[4];
        float w0[4], w1[4];
#pragma unroll
        for (int it = 0; it < 4; ++it) {
            const int t = tid + it * 1024;
            top2(logits, t, bf, b0[it], b1[it], w0[it], w1[it]);
            atomicAdd(&s_cnt[b0[it]], 1);
            atomicAdd(&s_cnt[b1[it]], 1);
        }
        __syncthreads();
        if (tid == 0) {
            int acc = 0;
            for (int e = 0; e < NEXP; ++e) {
                s_off[e] = acc; offsets[e] = acc; counts[e] = s_cnt[e];
                acc += s_cnt[e];
            }
        }
        __syncthreads();
#pragma unroll
        for (int it = 0; it < 4; ++it) {
            const int t = tid + it * 1024;
            int p0 = s_off[b0[it]] + atomicAdd(&s_cur[b0[it]], 1);
            pairinfo[p0] = 2 * t;     pairw[p0] = w0[it];
            int p1 = s_off[b1[it]] + atomicAdd(&s_cur[b1[it]], 1);
            pairinfo[p1] = 2 * t + 1; pairw[p1] = w1[it];
        }
        return;
    }

    // ---------------- conversion blocks (0..511) ----------------
    const long E0 = 524288;    // hid   [4096x1024]      (8-elem groups)
    const long E1 = 1048576;   // w13s  [4096x1024]
    const long E2 = 3145728;   // w13   [16x1024x1024]
    const long E3 = 4194304;   // w2    [16x1024x512]
    const long E4 = 4456448;   // w2s   [1024x2048]
    long i = (long)blockIdx.x * 1024 + tid;
    const long stride = 512L * 1024;
    for (; i < E4; i += stride) {
        const void* src; long j;
        if      (i < E0) { src = xs ? in4 : in0; j = i;      }
        else if (i < E1) { src = xs ? in0 : in4; j = i - E0; }
        else if (i < E2) { src = w13;            j = i - E1; }
        else if (i < E3) { src = w2;             j = i - E2; }
        else             { src = w2s;            j = i - E3; }
        uint4 v;
        if (bf) {
            v = ((const uint4*)src)[j];
        } else {
            float4 f0 = ((const float4*)src)[j * 2];
            float4 f1 = ((const float4*)src)[j * 2 + 1];
            v.x = (unsigned)f2bf(f0.x) | ((unsigned)f2bf(f0.y) << 16);
            v.y = (unsigned)f2bf(f0.z) | ((unsigned)f2bf(f0.w) << 16);
            v.z = (unsigned)f2bf(f1.x) | ((unsigned)f2bf(f1.y) << 16);
            v.w = (unsigned)f2bf(f1.z) | ((unsigned)f2bf(f1.w) << 16);
        }
        ((uint4*)dst)[i] = v;
    }
}

// setup_all + conv_all + to_bf16 retained for the FULL/MID/fallback tiers.
__global__ __launch_bounds__(1024)
void setup_all(const void* __restrict__ in0, const void* __restrict__ in4,
               const void* __restrict__ logits,
               int* __restrict__ dflag, int* __restrict__ xsel,
               int* __restrict__ counts, int* __restrict__ offsets,
               int* __restrict__ pairinfo, float* __restrict__ pairw)
{
    __shared__ int   s_cnt[16], s_off[16], s_cur[16];
    __shared__ int   s_dcnt, s_dflag, s_xsel;
    __shared__ float s0s, s4s;
    const int tid = threadIdx.x;

    if (tid < 16) { s_cnt[tid] = 0; s_cur[tid] = 0; }
    if (tid == 0) { s_dcnt = 0; s0s = 0.f; s4s = 0.f; }
    __syncthreads();
    if (tid < 256) {
        const ushort* xu = (const ushort*)in0;
        int ok = 0;
        for (int i = tid; i < 512; i += 256) {
            int e = (xu[2 * i] >> 7) & 0xFF;
            ok += (e >= 90 && e <= 140) ? 1 : 0;
        }
        atomicAdd(&s_dcnt, ok);
    }
    __syncthreads();
    if (tid == 0) { s_dflag = (s_dcnt >= 384) ? 1 : 0; *dflag = s_dflag; }
    __syncthreads();
    const int bf = s_dflag;
    if (tid < 256) {
        float a0 = 0.f, a4 = 0.f;
        for (int i = tid; i < 4096; i += 256) {
            a0 += fabsf(load_elem(in0, (long)i * 997 + 13, bf));
            a4 += fabsf(load_elem(in4, (long)i * 997 + 13, bf));
        }
        atomicAdd(&s0s, a0);
        atomicAdd(&s4s, a4);
    }
    __syncthreads();
    if (tid == 0) { s_xsel = (s0s >= s4s) ? 0 : 1; *xsel = s_xsel; }

    int   b0[4], b1[4];
    float w0[4], w1[4];
#pragma unroll
    for (int it = 0; it < 4; ++it) {
        const int t = tid + it * 1024;
        top2(logits, t, bf, b0[it], b1[it], w0[it], w1[it]);
        atomicAdd(&s_cnt[b0[it]], 1);
        atomicAdd(&s_cnt[b1[it]], 1);
    }
    __syncthreads();
    if (tid == 0) {
        int acc = 0;
        for (int e = 0; e < NEXP; ++e) {
            s_off[e] = acc; offsets[e] = acc; counts[e] = s_cnt[e];
            acc += s_cnt[e];
        }
    }
    __syncthreads();
#pragma unroll
    for (int it = 0; it < 4; ++it) {
        const int t = tid + it * 1024;
        int p0 = s_off[b0[it]] + atomicAdd(&s_cur[b0[it]], 1);
        pairinfo[p0] = 2 * t;     pairw[p0] = w0[it];
        int p1 = s_off[b1[it]] + atomicAdd(&s_cur[b1[it]], 1);
        pairinfo[p1] = 2 * t + 1; pairw[p1] = w1[it];
    }
}

__global__ __launch_bounds__(256)
void conv_all(const void* __restrict__ in0, const void* __restrict__ in4,
              const void* __restrict__ w13, const void* __restrict__ w2,
              const void* __restrict__ w2s, ushort* __restrict__ dst,
              const int* __restrict__ dflag, const int* __restrict__ xsel)
{
    const int bf = *dflag, xs = *xsel;
    const long E0 = 524288, E1 = 1048576, E2 = 3145728, E3 = 4194304, E4 = 4456448;
    long i = (long)blockIdx.x * blockDim.x + threadIdx.x;
    const long stride = (long)gridDim.x * blockDim.x;
    for (; i < E4; i += stride) {
        const void* src; long j;
        if      (i < E0) { src = xs ? in4 : in0; j = i;      }
        else if (i < E1) { src = xs ? in0 : in4; j = i - E0; }
        else if (i < E2) { src = w13;            j = i - E1; }
        else if (i < E3) { src = w2;             j = i - E2; }
        else             { src = w2s;            j = i - E3; }
        uint4 v;
        if (bf) {
            v = ((const uint4*)src)[j];
        } else {
            float4 f0 = ((const float4*)src)[j * 2];
            float4 f1 = ((const float4*)src)[j * 2 + 1];
            v.x = (unsigned)f2bf(f0.x) | ((unsigned)f2bf(f0.y) << 16);
            v.y = (unsigned)f2bf(f0.z) | ((unsigned)f2bf(f0.w) << 16);
            v.z = (unsigned)f2bf(f1.x) | ((unsigned)f2bf(f1.y) << 16);
            v.w = (unsigned)f2bf(f1.z) | ((unsigned)f2bf(f1.w) << 16);
        }
        ((uint4*)dst)[i] = v;
    }
}

__global__ void to_bf16(const void* __restrict__ pA, const void* __restrict__ pB,
                        ushort* __restrict__ dst, long n8,
                        const int* __restrict__ dflag, const int* __restrict__ xsel)
{
    const void* src = (pB != nullptr && *xsel) ? pB : pA;
    const int bf = *dflag;
    long i = (long)blockIdx.x * blockDim.x + threadIdx.x;
    const long stride = (long)gridDim.x * blockDim.x;
    for (; i < n8; i += stride) {
        uint4 v;
        if (bf) {
            v = ((const uint4*)src)[i];
        } else {
            float4 f0 = ((const float4*)src)[i * 2];
            float4 f1 = ((const float4*)src)[i * 2 + 1];
            v.x = (unsigned)f2bf(f0.x) | ((unsigned)f2bf(f0.y) << 16);
            v.y = (unsigned)f2bf(f0.z) | ((unsigned)f2bf(f0.w) << 16);
            v.z = (unsigned)f2bf(f1.x) | ((unsigned)f2bf(f1.y) << 16);
            v.w = (unsigned)f2bf(f1.z) | ((unsigned)f2bf(f1.w) << 16);
        }
        ((uint4*)dst)[i] = v;
    }
}

// ---------------------------------------------------------------------------
// m97-class bf16 NT GEMM core. 128-row tile, BK=64, 4 waves. Plain: BN=128
// (4x4 frags). SWIGLU: BN=64 gate+up. NARROW: BN=64 single-matrix.
// ATOM: fp32 outputs accumulate via atomicAdd (dst pre-zeroed).
// T2 swizzle (rule #21): linear global_load_lds dest + XOR-permuted per-lane
// global source col-group ((lane&7)^(lane>>3)) + matching XOR on fragment
// reads ((kc*4+quad)^(r16&7)). Bank conflicts measured 0 (round 4).
// ---------------------------------------------------------------------------
__device__ __forceinline__ void gload16(const ushort* g, ushort* l) {
    __builtin_amdgcn_global_load_lds((as1_void*)g, (as3_void*)l, 16, 0, 0);
}

template <int SWIGLU, int GATHER, int ROUTED, int SCATTER, int NARROW = 0, int ATOM = 0>
__device__ __forceinline__ void gemm_core(
    ushort* __restrict__ smem,
    const ushort* __restrict__ A, int lda,
    const ushort* __restrict__ B0, long upoff, long bbase, int ldb,
    void* __restrict__ C, int ldc, float* __restrict__ C2,
    int m0, int n0, int Mloc, int K, int pair_base,
    const int* __restrict__ pairinfo, const float* __restrict__ pairw)
{
    constexpr int BNRW = (SWIGLU || NARROW);   // 64-wide B tile
    constexpr int NBI = BNRW ? 2 : 4;
    constexpr int NFN = BNRW ? 2 : 4;

    ushort* As  = smem;                       // 128 x 64
    ushort* Bs0 = smem + 128 * 64;            // BN x 64
    ushort* Bs1 = SWIGLU ? (smem + 128 * 64 + 64 * 64) : nullptr;

    const int tid  = threadIdx.x;
    const int lane = tid & 63;
    const int wave = tid >> 6;
    const int srow = lane >> 3;
    const int scol = ((lane & 7) ^ srow) * 8;        // swizzled source col grp

    long aoff[4];
#pragma unroll
    for (int i = 0; i < 4; ++i) {
        int rl  = m0 + (wave * 4 + i) * 8 + srow;
        int rlc = rl < Mloc ? rl : Mloc - 1;
        long gr;
        if (GATHER)      gr = (long)(pairinfo[pair_base + rlc] >> 1);
        else if (ROUTED) gr = pair_base + rlc;
        else             gr = rlc;
        aoff[i] = gr * (long)lda + scol;
    }
    long boff[NBI];
#pragma unroll
    for (int i = 0; i < NBI; ++i) {
        int r = (wave * NBI + i) * 8 + srow;
        boff[i] = bbase + (long)(n0 + r) * ldb + scol;
    }

    const int wm   = (wave >> 1) * 64;
    const int wn   = (wave & 1) * (BNRW ? 32 : 64);
    const int r16  = lane & 15;
    const int quad = lane >> 4;
    const int rlow = r16 & 7;

    const floatx4 z4 = {0.f, 0.f, 0.f, 0.f};
    floatx4 accg[4][NFN], accu[4][NFN];
#pragma unroll
    for (int mi = 0; mi < 4; ++mi)
#pragma unroll
        for (int ni = 0; ni < NFN; ++ni) { accg[mi][ni] = z4; accu[mi][ni] = z4; }

    for (int k0 = 0; k0 < K; k0 += 64) {
#pragma unroll
        for (int i = 0; i < 4; ++i)
            gload16(A + aoff[i] + k0, &As[(wave * 4 + i) * 512]);
#pragma unroll
        for (int i = 0; i < NBI; ++i) {
            gload16(B0 + boff[i] + k0, &Bs0[(wave * NBI + i) * 512]);
            if constexpr (SWIGLU)
                gload16(B0 + boff[i] + upoff + k0, &Bs1[(wave * NBI + i) * 512]);
        }
        __syncthreads();
#pragma unroll
        for (int kc = 0; kc < 2; ++kc) {
            const int sw = ((kc * 4 + quad) ^ rlow) * 8;
            short8 af[4];
#pragma unroll
            for (int mi = 0; mi < 4; ++mi)
                af[mi] = *(const short8*)&As[(wm + mi * 16 + r16) * 64 + sw];
            short8 bfr[NFN], ufr[NFN];
#pragma unroll
            for (int ni = 0; ni < NFN; ++ni) {
                bfr[ni] = *(const short8*)&Bs0[(wn + ni * 16 + r16) * 64 + sw];
                if constexpr (SWIGLU)
                    ufr[ni] = *(const short8*)&Bs1[(wn + ni * 16 + r16) * 64 + sw];
            }
#pragma unroll
            for (int mi = 0; mi < 4; ++mi)
#pragma unroll
                for (int ni = 0; ni < NFN; ++ni) {
                    accg[mi][ni] = __builtin_amdgcn_mfma_f32_16x16x32_bf16(
                        af[mi], bfr[ni], accg[mi][ni], 0, 0, 0);
                    if constexpr (SWIGLU)
                        accu[mi][ni] = __builtin_amdgcn_mfma_f32_16x16x32_bf16(
                            af[mi], ufr[ni], accu[mi][ni], 0, 0, 0);
                }
        }
        __syncthreads();
    }

#pragma unroll
    for (int mi = 0; mi < 4; ++mi) {
#pragma unroll
        for (int r = 0; r < 4; ++r) {
            const int grow = m0 + wm + mi * 16 + quad * 4 + r;
            if (grow >= Mloc) continue;
            int info = 0; float w = 0.f;
            if constexpr (SCATTER) {
                const int p = pair_base + grow;
                info = pairinfo[p]; w = pairw[p];
            }
#pragma unroll
            for (int ni = 0; ni < NFN; ++ni) {
                const int col = n0 + wn + ni * 16 + r16;
                float val;
                if constexpr (SWIGLU) {
                    float g = accg[mi][ni][r];
                    float u = accu[mi][ni][r];
                    val = (g / (1.0f + __expf(-g))) * u;   // silu(g)*u
                } else {
                    val = accg[mi][ni][r];
                }
                if constexpr (SCATTER) {
                    long idx = (long)(info >> 1) * 1024 + col;
                    if constexpr (ATOM) {
                        atomicAdd((float*)C + idx, w * val);     // both ranks
                    } else {
                        float* dst = (info & 1) ? C2 : (float*)C;
                        dst[idx] = w * val;
                    }
                } else if constexpr (SWIGLU) {
                    long crow = ROUTED ? (long)(pair_base + grow) : (long)grow;
                    ((ushort*)C)[crow * ldc + col] = f2bf(val);   // bf16 act
                } else {
                    long idx = (long)grow * ldc + col;
                    if constexpr (ATOM) atomicAdd((float*)C + idx, val);
                    else                ((float*)C)[idx] = val;   // fp32 out
                }
            }
        }
    }
}

// XCD-aware bijective block remap (T1). N = nx*ny*nz must be divisible by 8.
__device__ __forceinline__ void xcd_swz(int& x, int& y, int& z,
                                        int nx, int ny, int nz) {
    int d = ((int)blockIdx.z * ny + (int)blockIdx.y) * nx + (int)blockIdx.x;
    const int N = nx * ny * nz;
    int L = (d & 7) * (N >> 3) + (d >> 3);
    x = L % nx; int t = L / nx; y = t % ny; z = t / ny;
}

// Thin wrapper (FULL / MID tiers).
template <int SWIGLU, int GATHER, int ROUTED, int SCATTER>
__global__ __launch_bounds__(256)
void gemm_fast(const ushort* __restrict__ A, int lda,
               const ushort* __restrict__ B0, long upoff, long strideB, int ldb,
               void* __restrict__ C, int ldc, float* __restrict__ C2,
               int M, int K,
               const int* __restrict__ counts, const int* __restrict__ offsets,
               const int* __restrict__ pairinfo, const float* __restrict__ pairw)
{
    __shared__ __align__(16) ushort smem[16384];
    const int e    = ROUTED ? (int)blockIdx.z : 0;
    const int Mloc = ROUTED ? counts[e] : M;
    const int m0   = blockIdx.y * 128;
    if (m0 >= Mloc) return;
    constexpr int BN = SWIGLU ? 64 : 128;
    const int n0  = blockIdx.x * BN;
    const int pb  = ROUTED ? offsets[e] : 0;
    const long bb = ROUTED ? (long)e * strideB : 0L;
    gemm_core<SWIGLU, GATHER, ROUTED, SCATTER>(
        smem, A, lda, B0, upoff, bb, ldb, C, ldc, C2,
        m0, n0, Mloc, K, pb, pairinfo, pairw);
}

// Fused L1: routed w13-SwiGLU (z<4, 4 experts per z-slice) + shared w13-SwiGLU
// (z==4). Grid (32, 32, 5), XCD-swizzled.
__global__ __launch_bounds__(256)
void g1_fused(const ushort* __restrict__ hidb, const ushort* __restrict__ w13b,
              const ushort* __restrict__ w13sb,
              ushort* __restrict__ actR, ushort* __restrict__ actS,
              const int* __restrict__ counts, const int* __restrict__ offsets,
              const int* __restrict__ pairinfo)
{
    __shared__ __align__(16) ushort smem[16384];
    int bx, by, bz;
    xcd_swz(bx, by, bz, 32, 32, 5);
    const int m0 = by * 128;
    if (bz < 4) {
        const int e    = bz * 4 + (bx >> 3);
        const int Mloc = counts[e];
        if (m0 >= Mloc) return;
        const int n0 = (bx & 7) * 64;
        gemm_core<1, 1, 1, 0>(smem, hidb, 1024,
                              w13b, (long)512 * 1024, (long)e * 1024 * 1024, 1024,
                              actR, 512, nullptr,
                              m0, n0, Mloc, 1024, offsets[e], pairinfo, nullptr);
    } else {
        const int n0 = bx * 64;
        gemm_core<1, 0, 0, 0>(smem, hidb, 1024,
                              w13sb, (long)2048 * 1024, 0L, 1024,
                              actS, 2048, nullptr,
                              m0, n0, T_TOK, 1024, 0, nullptr, nullptr);
    }
}

// Fused L2 (atomic): routed w2, both ranks atomicAdd->outF (z<4); shared w2
// split-K=2 packed into z==4 (bx>>4 = K-half), atomicAdd->outS.
// Grid (32, 32, 5), XCD-swizzled. d_out must be pre-zeroed.
__global__ __launch_bounds__(256)
void g2_fused(const ushort* __restrict__ actR, const ushort* __restrict__ actS,
              const ushort* __restrict__ w2b, const ushort* __restrict__ w2sb,
              float* __restrict__ outF, float* __restrict__ outS,
              const int* __restrict__ counts, const int* __restrict__ offsets,
              const int* __restrict__ pairinfo, const float* __restrict__ pairw)
{
    __shared__ __align__(16) ushort smem[16384];
    int bx, by, bz;
    xcd_swz(bx, by, bz, 32, 32, 5);
    const int m0 = by * 128;
    if (bz < 4) {
        const int e    = bz * 4 + (bx >> 3);
        const int Mloc = counts[e];
        if (m0 >= Mloc) return;
        const int n0 = (bx & 7) * 128;
        gemm_core<0, 0, 1, 1, 0, 1>(smem, actR, 512,
                                    w2b, 0L, (long)e * 1024 * 512, 512,
                                    outF, 1024, nullptr,
                                    m0, n0, Mloc, 512, offsets[e], pairinfo, pairw);
    } else {
        const int zz = bx >> 4;               // K-half index
        const int n0 = (bx & 15) * 64;
        gemm_core<0, 0, 0, 0, 1, 1>(smem, actS + zz * 1024, 2048,
                                    w2sb + zz * 1024, 0L, 0L, 2048,
                                    outS, 1024, nullptr,
                                    m0, n0, T_TOK, 1024, 0, nullptr, nullptr);
    }
}

// outF[i] += outT[i]   (FULL/MID/fallback tiers)
__global__ void add_kernel(float* __restrict__ outF, const float* __restrict__ outT, int n4) {
    int i = blockIdx.x * blockDim.x + threadIdx.x;
    if (i >= n4) return;
    float4 a = *(const float4*)(outF + (long)i * 4);
    float4 b = *(const float4*)(outT + (long)i * 4);
    a.x += b.x; a.y += b.y; a.z += b.z; a.w += b.w;
    *(float4*)(outF + (long)i * 4) = a;
}

// ---------------------------------------------------------------------------
// Fallback GEMM (original session kernel) — tiny-ws insurance only.
// ---------------------------------------------------------------------------
__device__ __forceinline__ void stage8(const void* __restrict__ src, long eoff, int bf,
                                       ushort* __restrict__ dst) {
    if (bf) {
        *(uint4*)dst = *(const uint4*)((const ushort*)src + eoff);
    } else {
        const float* s = (const float*)src + eoff;
        float4 f0 = *(const float4*)s;
        float4 f1 = *(const float4*)(s + 4);
        uint4 v;
        v.x = (unsigned)f2bf(f0.x) | ((unsigned)f2bf(f0.y) << 16);
        v.y = (unsigned)f2bf(f0.z) | ((unsigned)f2bf(f0.w) << 16);
        v.z = (unsigned)f2bf(f1.x) | ((unsigned)f2bf(f1.y) << 16);
        v.w = (unsigned)f2bf(f1.z) | ((unsigned)f2bf(f1.w) << 16);
        *(uint4*)dst = v;
    }
}

template <int SWIGLU, int GATHER, int ROUTED, int SCATTER, int LOCAL,
          int A_DT, int B_DT, int C_F32>
__global__ __launch_bounds__(256)
void gemm_nt(const void* __restrict__ A, const void* __restrict__ Aalt, int lda,
             const void* __restrict__ B0, const void* __restrict__ B0alt,
             long upoff, long strideB,
             void* __restrict__ C, int ldc, void* __restrict__ C2,
             int M, int K, int row0,
             const int* __restrict__ dflag, const int* __restrict__ xsel,
             const int* __restrict__ counts, const int* __restrict__ offsets,
             const int* __restrict__ pairinfo, const float* __restrict__ pairw,
             int e_base, int m_base, int Mcap)
{
    const int dfl = (A_DT && B_DT) ? 1 : *dflag;
    const int abf = A_DT ? 1 : dfl;
    const int bbf = B_DT ? 1 : dfl;
    if (Aalt  && *xsel) A  = Aalt;
    if (B0alt && *xsel) B0 = B0alt;

    const int e = ROUTED ? (e_base + (int)blockIdx.z) : 0;
    int Mloc;
    if (ROUTED) {
        int avail = counts[e] - m_base;
        Mloc = avail < Mcap ? avail : Mcap;
    } else {
        Mloc = M;
    }
    const int m0 = blockIdx.y * 64;
    if (m0 >= Mloc) return;
    const int n0 = blockIdx.x * 64;
    const int pair_base = ROUTED ? (offsets[e] + m_base) : 0;
    const int abase     = ROUTED ? (LOCAL ? 0 : offsets[e]) : 0;
    const long bbase    = ROUTED ? (long)e * strideB : 0L;

    constexpr int LS = 72;
    __shared__ __align__(16) ushort As[64 * LS];
    __shared__ __align__(16) ushort Bs0[64 * LS];
    __shared__ __align__(16) ushort Bs1[SWIGLU ? 64 * LS : 8];

    const int tid = threadIdx.x;

    int  lofs[2];
    long aoff[2], boff[2];
#pragma unroll
    for (int i = 0; i < 2; ++i) {
        int idx = tid + i * 256;
        int row = idx >> 3;
        int col = (idx & 7) * 8;
        lofs[i] = row * LS + col;
        int rl  = m0 + row;
        int rlc = rl < Mloc ? rl : (Mloc - 1);
        long rA;
        if (GATHER)      rA = (long)(pairinfo[pair_base + rlc] >> 1);
        else if (ROUTED) rA = abase + rlc;
        else             rA = row0 + rl;
        aoff[i] = rA * (long)lda + col;
        boff[i] = bbase + (long)(n0 + row) * K + col;
    }

    const int lane = tid & 63;
    const int wave = tid >> 6;
    const int wm   = (wave >> 1) * 32;
    const int wn   = (wave & 1) * 32;
    const int r16  = lane & 15;
    const int quad = lane >> 4;

    floatx4 accg[2][2] = {{{0.f,0.f,0.f,0.f},{0.f,0.f,0.f,0.f}},{{0.f,0.f,0.f,0.f},{0.f,0.f,0.f,0.f}}};
    floatx4 accu[2][2] = {{{0.f,0.f,0.f,0.f},{0.f,0.f,0.f,0.f}},{{0.f,0.f,0.f,0.f},{0.f,0.f,0.f,0.f}}};

    for (int k0 = 0; k0 < K; k0 += 64) {
#pragma unroll
        for (int i = 0; i < 2; ++i) {
            stage8(A,  aoff[i] + k0, abf, &As[lofs[i]]);
            stage8(B0, boff[i] + k0, bbf, &Bs0[lofs[i]]);
            if (SWIGLU) stage8(B0, boff[i] + k0 + upoff, bbf, &Bs1[lofs[i]]);
        }
        __syncthreads();
#pragma unroll
        for (int kc = 0; kc < 2; ++kc) {
            const int kof = kc * 32 + quad * 8;
            short8 a0 = *(const short8*)&As[(wm + r16)      * LS + kof];
            short8 a1 = *(const short8*)&As[(wm + 16 + r16) * LS + kof];
            short8 b0 = *(const short8*)&Bs0[(wn + r16)      * LS + kof];
            short8 b1 = *(const short8*)&Bs0[(wn + 16 + r16) * LS + kof];
            accg[0][0] = __builtin_amdgcn_mfma_f32_16x16x32_bf16(a0, b0, accg[0][0], 0, 0, 0);
            accg[0][1] = __builtin_amdgcn_mfma_f32_16x16x32_bf16(a0, b1, accg[0][1], 0, 0, 0);
            accg[1][0] = __builtin_amdgcn_mfma_f32_16x16x32_bf16(a1, b0, accg[1][0], 0, 0, 0);
            accg[1][1] = __builtin_amdgcn_mfma_f32_16x16x32_bf16(a1, b1, accg[1][1], 0, 0, 0);
            if (SWIGLU) {
                short8 u0 = *(const short8*)&Bs1[(wn + r16)      * LS + kof];
                short8 u1 = *(const short8*)&Bs1[(wn + 16 + r16) * LS + kof];
                accu[0][0] = __builtin_amdgcn_mfma_f32_16x16x32_bf16(a0, u0, accu[0][0], 0, 0, 0);
                accu[0][1] = __builtin_amdgcn_mfma_f32_16x16x32_bf16(a0, u1, accu[0][1], 0, 0, 0);
                accu[1][0] = __builtin_amdgcn_mfma_f32_16x16x32_bf16(a1, u0, accu[1][0], 0, 0, 0);
                accu[1][1] = __builtin_amdgcn_mfma_f32_16x16x32_bf16(a1, u1, accu[1][1], 0, 0, 0);
            }
        }
        __syncthreads();
    }

#pragma unroll
    for (int mi = 0; mi < 2; ++mi) {
#pragma unroll
        for (int ni = 0; ni < 2; ++ni) {
#pragma unroll
            for (int r = 0; r < 4; ++r) {
                int rowl = wm + mi * 16 + quad * 4 + r;
                int grow = m0 + rowl;
                if (grow < Mloc) {
                    int col = n0 + wn + ni * 16 + r16;
                    float g = accg[mi][ni][r];
                    float val;
                    if (SWIGLU) {
                        float u = accu[mi][ni][r];
                        val = (g / (1.0f + __expf(-g))) * u;
                    } else {
                        val = g;
                    }
                    if (SCATTER) {
                        int p    = pair_base + grow;
                        int info = pairinfo[p];
                        float w  = pairw[p];
                        long idx = (long)(info >> 1) * 1024 + col;
                        void* dst = (info & 1) ? C2 : C;
                        if (C_F32) ((float*)dst)[idx]  = w * val;
                        else       ((ushort*)dst)[idx] = f2bf(w * val);
                    } else {
                        int crow = ROUTED ? (abase + grow) : grow;
                        long idx = (long)crow * ldc + col;
                        if (C_F32) ((float*)C)[idx]  = val;
                        else       ((ushort*)C)[idx] = f2bf(val);
                    }
                }
            }
        }
    }
}

// ---------------------------------------------------------------------------
extern "C" void kernel_launch(void* const* d_in, const int* in_sizes, int n_in,
                              void* d_out, int out_size, void* d_ws, size_t ws_size,
                              hipStream_t stream)
{
    const void* in0  = d_in[0];  // hidden_states [4096,1024] fp32
    const void* rl   = d_in[1];  // router_logits [4096,16]
    const void* w13  = d_in[2];  // [16,1024,1024]
    const void* w2   = d_in[3];  // [16,1024,512]
    const void* in4  = d_in[4];  // w13_shared [4096,1024]
    const void* w2s  = d_in[5];  // w2_shared [1024,2048]
    float* outS = (float*)d_out;                          // shared (final)
    float* outF = (float*)d_out + (size_t)T_TOK * 1024;   // fused (final)

    // ---- metadata layout (66 KB) ----
    char*  base     = (char*)d_ws;
    int*   counts   = (int*)(base);
    int*   dflag    = (int*)(base + 128);
    int*   xsel     = (int*)(base + 132);
    int*   offsets  = (int*)(base + 192);
    int*   pairinfo = (int*)(base + 256);
    float* pairw    = (float*)(base + 256 + 32768);
    const size_t META = 256 + 65536;

    size_t avail = ws_size > META ? ws_size - META : 0;

    const long sB1  = (long)1024 * 1024;   // w13 per-expert elements
    const long sB2  = (long)1024 * 512;    // w2 per-expert elements
    const long UP_R = (long)512 * 1024;    // routed up-offset within expert block
    const long UP_S = (long)2048 * 1024;   // shared up-offset in w13s

    const size_t FULL2_NEED = 96468992ULL;  // all-bf16 + actR + actS
    const size_t FULL_NEED  = 88080384ULL;  // all-bf16 + single shared act
    const size_t MID_NEED   = 29360128ULL;  // act + hid + w13s + w2s bf16

    if (avail >= FULL2_NEED) {
        // ====== FULL2: 4 nodes = memset + conv_plus + g1 + g2(atomic) =====
        ushort* hidb  = (ushort*)(base + META);
        ushort* w13sb = hidb  + (size_t)4096 * 1024;
        ushort* w13b  = w13sb + (size_t)4096 * 1024;
        ushort* w2b   = w13b  + (size_t)16 * 1024 * 1024;
        ushort* w2sb  = w2b   + (size_t)16 * 1024 * 512;
        ushort* actR  = w2sb  + (size_t)1024 * 2048;     // [8192, 512] bf16
        ushort* actS  = actR  + (size_t)8192 * 512;      // [4096, 2048] bf16

        hipMemsetAsync(d_out, 0, out_size, stream);      // outS + outF zeroed
        conv_plus<<<513, 1024, 0, stream>>>(in0, in4, w13, w2, w2s, hidb, rl,
                                            dflag, xsel, counts, offsets,
                                            pairinfo, pairw);
        g1_fused<<<dim3(32, 32, 5), 256, 0, stream>>>(
            hidb, w13b, w13sb, actR, actS, counts, offsets, pairinfo);
        g2_fused<<<dim3(32, 32, 5), 256, 0, stream>>>(
            actR, actS, w2b, w2sb, outF, outS,
            counts, offsets, pairinfo, pairw);
    } else if (avail >= FULL_NEED) {
        // ====== FULL: bf16 everywhere, sequential plain-store launches =====
        ushort* hidb  = (ushort*)(base + META);
        ushort* w13sb = hidb  + (size_t)4096 * 1024;
        ushort* w13b  = w13sb + (size_t)4096 * 1024;
        ushort* w2b   = w13b  + (size_t)16 * 1024 * 1024;
        ushort* w2sb  = w2b   + (size_t)16 * 1024 * 512;
        ushort* actb  = w2sb  + (size_t)1024 * 2048;

        setup_all<<<1, 1024, 0, stream>>>(in0, in4, rl, dflag, xsel,
                                          counts, offsets, pairinfo, pairw);
        conv_all<<<2048, 256, 0, stream>>>(in0, in4, w13, w2, w2s,
                                           hidb, dflag, xsel);

        gemm_fast<1,1,1,0><<<dim3(8, 32, NEXP), 256, 0, stream>>>(
            hidb, 1024, w13b, UP_R, sB1, 1024, actb, 512, nullptr, 0, 1024,
            counts, offsets, pairinfo, pairw);
        gemm_fast<0,0,1,1><<<dim3(8, 32, NEXP), 256, 0, stream>>>(
            actb, 512, w2b, 0, sB2, 512, outF, 1024, outS, 0, 512,
            counts, offsets, pairinfo, pairw);
        add_kernel<<<(T_TOK * 1024 / 4 + 255) / 256, 256, 0, stream>>>(outF, outS, T_TOK * 1024 / 4);
        gemm_fast<1,0,0,0><<<dim3(32, 32), 256, 0, stream>>>(
            hidb, 1024, w13sb, UP_S, 0, 1024, actb, 2048, nullptr, 4096, 1024,
            nullptr, nullptr, nullptr, nullptr);
        gemm_fast<0,0,0,0><<<dim3(8, 32), 256, 0, stream>>>(
            actb, 2048, w2sb, 0, 0, 2048, outS, 1024, nullptr, 4096, 2048,
            nullptr, nullptr, nullptr, nullptr);
    } else if (avail >= MID_NEED) {
        // ========== MID: fast shared path + improved old routed path =======
        ushort* act   = (ushort*)(base + META);
        ushort* hidb  = act   + (size_t)8192 * 512;
        ushort* w13sb = hidb  + (size_t)4096 * 1024;
        ushort* w2sb  = w13sb + (size_t)4096 * 1024;

        setup_all<<<1, 1024, 0, stream>>>(in0, in4, rl, dflag, xsel,
                                          counts, offsets, pairinfo, pairw);
        to_bf16<<<1024, 256, 0, stream>>>(in0, in4, hidb,  (long)4096 * 1024 / 8, dflag, xsel);
        to_bf16<<<1024, 256, 0, stream>>>(in4, in0, w13sb, (long)4096 * 1024 / 8, dflag, xsel);
        to_bf16<<<1024, 256, 0, stream>>>(w2s, nullptr, w2sb, (long)1024 * 2048 / 8, dflag, xsel);

        gemm_nt<1,1,1,0,0,1,0,0><<<dim3(8, 64, NEXP), 256, 0, stream>>>(
            hidb, nullptr, 1024, w13, nullptr, UP_R, sB1, act, 512, nullptr, 0, 1024, 0,
            dflag, xsel, counts, offsets, pairinfo, pairw, 0, 0, T_TOK);
        gemm_nt<0,0,1,1,0,1,0,1><<<dim3(16, 64, NEXP), 256, 0, stream>>>(
            act, nullptr, 512, w2, nullptr, 0, sB2, outF, 1024, outS, 0, 512, 0,
            dflag, xsel, counts, offsets, pairinfo, pairw, 0, 0, T_TOK);
        add_kernel<<<(T_TOK * 1024 / 4 + 255) / 256, 256, 0, stream>>>(outF, outS, T_TOK * 1024 / 4);
        for (int c = 0; c < 2; ++c) {
            gemm_fast<1,0,0,0><<<dim3(32, 16), 256, 0, stream>>>(
                hidb + (size_t)c * 2048 * 1024, 1024, w13sb, UP_S, 0, 1024,
                act, 2048, nullptr, 2048, 1024, nullptr, nullptr, nullptr, nullptr);
            gemm_fast<0,0,0,0><<<dim3(8, 16), 256, 0, stream>>>(
                act, 2048, w2sb, 0, 0, 2048, outS + (size_t)c * 2048 * 1024, 1024, nullptr,
                2048, 2048, nullptr, nullptr, nullptr, nullptr);
        }
    } else {
        // ===================== fallback: original kernel ===================
        const size_t MB = 1024 * 1024;
        int grouped, Mcap, CH;
        if      (avail >= 8 * MB) { grouped = 1; Mcap = T_TOK; CH = 2048; }
        else if (avail >= 1 * MB) { grouped = 0; Mcap = 1024;  CH = 256;  }
        else                      { grouped = 0; Mcap = 256;   CH = 64;   }
        ushort* act = (ushort*)(base + META);

        setup_all<<<1, 1024, 0, stream>>>(in0, in4, rl, dflag, xsel,
                                          counts, offsets, pairinfo, pairw);
        if (grouped) {
            gemm_nt<1,1,1,0,0,0,0,0><<<dim3(8, 64, NEXP), 256, 0, stream>>>(
                in0, in4, 1024, w13, nullptr, UP_R, sB1, act, 512, nullptr, 0, 1024, 0,
                dflag, xsel, counts, offsets, pairinfo, pairw, 0, 0, T_TOK);
            gemm_nt<0,0,1,1,0,1,0,1><<<dim3(16, 64, NEXP), 256, 0, stream>>>(
                act, nullptr, 512, w2, nullptr, 0, sB2, outF, 1024, outS, 0, 512, 0,
                dflag, xsel, counts, offsets, pairinfo, pairw, 0, 0, T_TOK);
        } else {
            for (int e = 0; e < NEXP; ++e) {
                for (int mb = 0; mb < T_TOK; mb += Mcap) {
                    gemm_nt<1,1,1,0,1,0,0,0><<<dim3(8, Mcap / 64, 1), 256, 0, stream>>>(
                        in0, in4, 1024, w13, nullptr, UP_R, sB1, act, 512, nullptr, 0, 1024, 0,
                        dflag, xsel, counts, offsets, pairinfo, pairw, e, mb, Mcap);
                    gemm_nt<0,0,1,1,1,1,0,1><<<dim3(16, Mcap / 64, 1), 256, 0, stream>>>(
                        act, nullptr, 512, w2, nullptr, 0, sB2, outF, 1024, outS, 0, 512, 0,
                        dflag, xsel, counts, offsets, pairinfo, pairw, e, mb, Mcap);
                }
            }
        }
        add_kernel<<<(T_TOK * 1024 / 4 + 255) / 256, 256, 0, stream>>>(outF, outS, T_TOK * 1024 / 4);
        for (int c = 0; c < T_TOK / CH; ++c) {
            gemm_nt<1,0,0,0,0,0,0,0><<<dim3(2048 / 64, CH / 64), 256, 0, stream>>>(
                in0, in4, 1024, in4, in0, UP_S, 0, act, 2048, nullptr, CH, 1024, c * CH,
                dflag, xsel, nullptr, nullptr, nullptr, nullptr, 0, 0, 0);
            gemm_nt<0,0,0,0,0,1,0,1><<<dim3(1024 / 64, CH / 64), 256, 0, stream>>>(
                act, nullptr, 2048, w2s, nullptr, 0, 0,
                outS + (size_t)c * CH * 1024, 1024, nullptr, CH, 2048, 0,
                dflag, xsel, nullptr, nullptr, nullptr, nullptr, 0, 0, 0);
        }
    }
    (void)in_sizes; (void)n_in; (void)out_size;
}